// Round 3
// baseline (46.184 us; speedup 1.0000x reference)
//
#include <hip/hip_runtime.h>

typedef float  f32x4 __attribute__((ext_vector_type(4)));
typedef short  s16x8 __attribute__((ext_vector_type(8)));

constexpr int D  = 128;   // feature dim
constexpr int K  = 512;   // RBF kernels
constexpr int O  = 256;   // output dim
constexpr int NT = 256;   // threads per block

__device__ __forceinline__ ushort f2bf(float f) {
    uint u = __builtin_bit_cast(uint, f);
    return (ushort)((u + 0x7FFFu + ((u >> 16) & 1u)) >> 16);
}
__device__ __forceinline__ float bf2f(ushort h) {
    uint u = ((uint)h) << 16;
    return __builtin_bit_cast(float, u);
}

// ---------------- prep: convert operands to bf16 (hi/lo) + row stats ----------------
__global__ __launch_bounds__(NT)
void rbf_prep(const float* __restrict__ x, const float* __restrict__ cen,
              const float* __restrict__ ls, const float* __restrict__ w,
              ushort* __restrict__ Xhi, ushort* __restrict__ Xlo,
              ushort* __restrict__ Chi, ushort* __restrict__ Clo,
              ushort* __restrict__ Wb,  float* __restrict__ xs2,
              float2* __restrict__ ecs, int xb)
{
    const int b = blockIdx.x, t = threadIdx.x;
    if (b < xb) {                       // ---- X: convert + ||x||^2 ----
        int f = b * NT + t;             // float4 index
        int row = f >> 5, q = f & 31;
        float4 v = reinterpret_cast<const float4*>(x)[f];
        ushort4 h, lo;
        h.x = f2bf(v.x); lo.x = f2bf(v.x - bf2f(h.x));
        h.y = f2bf(v.y); lo.y = f2bf(v.y - bf2f(h.y));
        h.z = f2bf(v.z); lo.z = f2bf(v.z - bf2f(h.z));
        h.w = f2bf(v.w); lo.w = f2bf(v.w - bf2f(h.w));
        *reinterpret_cast<ushort4*>(&Xhi[(size_t)f * 4]) = h;
        *reinterpret_cast<ushort4*>(&Xlo[(size_t)f * 4]) = lo;
        float s = v.x*v.x + v.y*v.y + v.z*v.z + v.w*v.w;
        s += __shfl_xor(s, 1);  s += __shfl_xor(s, 2);
        s += __shfl_xor(s, 4);  s += __shfl_xor(s, 8);
        s += __shfl_xor(s, 16);
        if (q == 0) xs2[row] = s;
    } else if (b < xb + 64) {           // ---- C: convert + fused (es, es*||c||^2) ----
        int f = (b - xb) * NT + t;
        int row = f >> 5, q = f & 31;
        float4 v = reinterpret_cast<const float4*>(cen)[f];
        ushort4 h, lo;
        h.x = f2bf(v.x); lo.x = f2bf(v.x - bf2f(h.x));
        h.y = f2bf(v.y); lo.y = f2bf(v.y - bf2f(h.y));
        h.z = f2bf(v.z); lo.z = f2bf(v.z - bf2f(h.z));
        h.w = f2bf(v.w); lo.w = f2bf(v.w - bf2f(h.w));
        *reinterpret_cast<ushort4*>(&Chi[(size_t)f * 4]) = h;
        *reinterpret_cast<ushort4*>(&Clo[(size_t)f * 4]) = lo;
        float s = v.x*v.x + v.y*v.y + v.z*v.z + v.w*v.w;
        s += __shfl_xor(s, 1);  s += __shfl_xor(s, 2);
        s += __shfl_xor(s, 4);  s += __shfl_xor(s, 8);
        s += __shfl_xor(s, 16);
        if (q == 0) {
            float e = __expf(2.0f * ls[row]);
            ecs[row] = make_float2(e, e * s);
        }
    } else {                            // ---- W: convert ----
        int f = (b - xb - 64) * NT + t; // 0 .. O*K/4-1
        float4 v = reinterpret_cast<const float4*>(w)[f];
        ushort4 h;
        h.x = f2bf(v.x); h.y = f2bf(v.y);
        h.z = f2bf(v.z); h.w = f2bf(v.w);
        *reinterpret_cast<ushort4*>(&Wb[(size_t)f * 4]) = h;
    }
}

// ---------------- main: register-direct MFMA, LDS only for the P transpose ----------------
constexpr int BN  = 16;     // rows per block
constexpr int KT  = 64;     // kernel tile
constexpr int KTP = KT + 8; // padded P row

__global__ __launch_bounds__(NT, 4)
void rbf_main(const ushort* __restrict__ Xhi, const ushort* __restrict__ Xlo,
              const ushort* __restrict__ Chi, const ushort* __restrict__ Clo,
              const ushort* __restrict__ Wb,  const float* __restrict__ xs2,
              const float2* __restrict__ ecs, float* __restrict__ out)
{
    __shared__ ushort Ps[2][BN][KTP];
    __shared__ float  Ls[4][BN];

    const int t    = threadIdx.x;
    const int lane = t & 63;
    const int wv   = t >> 6;      // 0..3
    const int l15  = lane & 15;
    const int l4   = lane >> 4;   // 0..3
    const int nb   = blockIdx.x * BN;

    // hoist X fragments (invariant over k) + row norms
    s16x8 xh[4], xl[4];
#pragma unroll
    for (int ds = 0; ds < 4; ++ds) {
        size_t off = (size_t)(nb + l15) * D + ds * 32 + l4 * 8;
        xh[ds] = *reinterpret_cast<const s16x8*>(&Xhi[off]);
        xl[ds] = *reinterpret_cast<const s16x8*>(&Xlo[off]);
    }
    float xs2v[4];
#pragma unroll
    for (int r = 0; r < 4; ++r) xs2v[r] = xs2[nb + l4 * 4 + r];

    f32x4 oacc[4];
#pragma unroll
    for (int ot = 0; ot < 4; ++ot) oacc[ot] = (f32x4){0.f, 0.f, 0.f, 0.f};
    float Lp[4] = {0.f, 0.f, 0.f, 0.f};

    int cur = 0;
    for (int kt = 0; kt < K / KT; ++kt) {
        const int k0 = kt * KT;
        const int kg = k0 + wv * 16 + l15;   // this wave's G column

        // GEMM1 B fragments direct from global (L2-resident)
        s16x8 ch[4], cl[4];
#pragma unroll
        for (int ds = 0; ds < 4; ++ds) {
            size_t off = (size_t)kg * D + ds * 32 + l4 * 8;
            ch[ds] = *reinterpret_cast<const s16x8*>(&Chi[off]);
            cl[ds] = *reinterpret_cast<const s16x8*>(&Clo[off]);
        }
        f32x4 g = (f32x4){0.f, 0.f, 0.f, 0.f};
#pragma unroll
        for (int ds = 0; ds < 4; ++ds) {
            g = __builtin_amdgcn_mfma_f32_16x16x32_bf16(xh[ds], ch[ds], g, 0, 0, 0);
            g = __builtin_amdgcn_mfma_f32_16x16x32_bf16(xh[ds], cl[ds], g, 0, 0, 0);
            g = __builtin_amdgcn_mfma_f32_16x16x32_bf16(xl[ds], ch[ds], g, 0, 0, 0);
        }

        // phi = exp(-es*(||x||^2 + ||c||^2 - 2 x.c)) with fused (es, es*cs2)
        float2 ec = ecs[kg];
#pragma unroll
        for (int r = 0; r < 4; ++r) {
            float arg = fmaf(ec.x, fmaf(-2.0f, g[r], xs2v[r]), ec.y);
            float ph  = __expf(-arg);
            Lp[r] += ph;
            Ps[cur][l4 * 4 + r][wv * 16 + l15] = f2bf(ph);
        }
        __syncthreads();

        // GEMM2: out += phi . W^T, B fragments direct from global (L2-resident)
        s16x8 a0 = *reinterpret_cast<const s16x8*>(&Ps[cur][l15][l4 * 8]);
        s16x8 a1 = *reinterpret_cast<const s16x8*>(&Ps[cur][l15][32 + l4 * 8]);
#pragma unroll
        for (int ot = 0; ot < 4; ++ot) {
            size_t wrow = (size_t)(wv * 64 + ot * 16 + l15) * K + k0;
            s16x8 b0 = *reinterpret_cast<const s16x8*>(&Wb[wrow + l4 * 8]);
            oacc[ot] = __builtin_amdgcn_mfma_f32_16x16x32_bf16(a0, b0, oacc[ot], 0, 0, 0);
            s16x8 b1 = *reinterpret_cast<const s16x8*>(&Wb[wrow + 32 + l4 * 8]);
            oacc[ot] = __builtin_amdgcn_mfma_f32_16x16x32_bf16(a1, b1, oacc[ot], 0, 0, 0);
        }
        cur ^= 1;
    }

    // row-sum reduce: over l15 lanes, then across waves via LDS
#pragma unroll
    for (int r = 0; r < 4; ++r) {
        float s = Lp[r];
        s += __shfl_xor(s, 1);  s += __shfl_xor(s, 2);
        s += __shfl_xor(s, 4);  s += __shfl_xor(s, 8);
        if (l15 == 0) Ls[wv][l4 * 4 + r] = s;
    }
    __syncthreads();

    // epilogue: normalize + store
#pragma unroll
    for (int r = 0; r < 4; ++r) {
        int n = l4 * 4 + r;
        float inv = 1.0f / (Ls[0][n] + Ls[1][n] + Ls[2][n] + Ls[3][n] + 1e-9f);
#pragma unroll
        for (int ot = 0; ot < 4; ++ot) {
            out[(size_t)(nb + n) * O + wv * 64 + ot * 16 + l15] = oacc[ot][r] * inv;
        }
    }
}

// ---------------- fallback (round-2 kernel) if ws is too small ----------------
constexpr int FBN = 32, FKT = 32;
constexpr int FDP = D + 8, FWP = FKT + 8;

__global__ __launch_bounds__(NT)
void rbf_fb(const float* __restrict__ x, const float* __restrict__ cen,
            const float* __restrict__ ls, const float* __restrict__ w,
            float* __restrict__ out)
{
    __shared__ ushort Xh[FBN][FDP], Xl[FBN][FDP];
    __shared__ ushort Ch[FKT][FDP], Cl[FKT][FDP];
    __shared__ ushort Ws[O][FWP];
    __shared__ ushort Pt[FBN][FWP];
    __shared__ float  es[K], sx2[FBN], sc2[FKT], L2[2][FBN];

    const int t = threadIdx.x, lane = t & 63, wv = t >> 6;
    const int nh = wv >> 1, kh = wv & 1, l15 = lane & 15, l4 = lane >> 4;
    const int nb = blockIdx.x * FBN;

    for (int i = t; i < K; i += NT) es[i] = __expf(2.0f * ls[i]);
    {
        const float4* x4 = reinterpret_cast<const float4*>(x + (size_t)nb * D);
#pragma unroll
        for (int i = 0; i < 4; ++i) {
            int f = t + i * NT, row = f >> 5, q = f & 31;
            float4 v = x4[row * 32 + q];
            ushort4 h, lo;
            h.x = f2bf(v.x); lo.x = f2bf(v.x - bf2f(h.x));
            h.y = f2bf(v.y); lo.y = f2bf(v.y - bf2f(h.y));
            h.z = f2bf(v.z); lo.z = f2bf(v.z - bf2f(h.z));
            h.w = f2bf(v.w); lo.w = f2bf(v.w - bf2f(h.w));
            *(ushort4*)&Xh[row][q * 4] = h; *(ushort4*)&Xl[row][q * 4] = lo;
            float s = v.x*v.x + v.y*v.y + v.z*v.z + v.w*v.w;
            s += __shfl_xor(s, 1); s += __shfl_xor(s, 2);
            s += __shfl_xor(s, 4); s += __shfl_xor(s, 8); s += __shfl_xor(s, 16);
            if (q == 0) sx2[row] = s;
        }
    }
    f32x4 oc2[2][4];
#pragma unroll
    for (int a = 0; a < 2; ++a)
#pragma unroll
        for (int b = 0; b < 4; ++b) oc2[a][b] = (f32x4){0.f,0.f,0.f,0.f};
    float Lp[4] = {0.f,0.f,0.f,0.f};
    const float4* c4 = reinterpret_cast<const float4*>(cen);
    const float4* w4 = reinterpret_cast<const float4*>(w);

    for (int kt = 0; kt < K / FKT; ++kt) {
        const int k0 = kt * FKT;
#pragma unroll
        for (int i = 0; i < 4; ++i) {
            int f = t + i * NT, row = f >> 5, q = f & 31;
            float4 v = c4[(size_t)(k0 + row) * 32 + q];
            ushort4 h, lo;
            h.x = f2bf(v.x); lo.x = f2bf(v.x - bf2f(h.x));
            h.y = f2bf(v.y); lo.y = f2bf(v.y - bf2f(h.y));
            h.z = f2bf(v.z); lo.z = f2bf(v.z - bf2f(h.z));
            h.w = f2bf(v.w); lo.w = f2bf(v.w - bf2f(h.w));
            *(ushort4*)&Ch[row][q * 4] = h; *(ushort4*)&Cl[row][q * 4] = lo;
            float s = v.x*v.x + v.y*v.y + v.z*v.z + v.w*v.w;
            s += __shfl_xor(s, 1); s += __shfl_xor(s, 2);
            s += __shfl_xor(s, 4); s += __shfl_xor(s, 8); s += __shfl_xor(s, 16);
            if (q == 0) sc2[row] = s;
        }
#pragma unroll
        for (int i = 0; i < 8; ++i) {
            int f = t + i * NT, o = f >> 3, q = f & 7;
            float4 v = w4[(size_t)o * (K / 4) + kt * 8 + q];
            ushort4 h;
            h.x = f2bf(v.x); h.y = f2bf(v.y); h.z = f2bf(v.z); h.w = f2bf(v.w);
            *(ushort4*)&Ws[o][q * 4] = h;
        }
        __syncthreads();
        f32x4 g = (f32x4){0.f,0.f,0.f,0.f};
#pragma unroll
        for (int ds = 0; ds < 4; ++ds) {
            int dc = ds * 32 + l4 * 8;
            s16x8 ah = *(const s16x8*)&Xh[nh*16+l15][dc];
            s16x8 al = *(const s16x8*)&Xl[nh*16+l15][dc];
            s16x8 bh = *(const s16x8*)&Ch[kh*16+l15][dc];
            s16x8 bl = *(const s16x8*)&Cl[kh*16+l15][dc];
            g = __builtin_amdgcn_mfma_f32_16x16x32_bf16(ah, bh, g, 0, 0, 0);
            g = __builtin_amdgcn_mfma_f32_16x16x32_bf16(ah, bl, g, 0, 0, 0);
            g = __builtin_amdgcn_mfma_f32_16x16x32_bf16(al, bh, g, 0, 0, 0);
        }
#pragma unroll
        for (int r = 0; r < 4; ++r) {
            int nl = nh*16 + l4*4 + r, kl = kh*16 + l15;
            float r2 = sx2[nl] + sc2[kl] - 2.0f * g[r];
            float ph = __expf(-es[k0+kl] * r2);
            Lp[r] += ph;
            Pt[nl][kl] = f2bf(ph);
        }
        __syncthreads();
#pragma unroll
        for (int nt2 = 0; nt2 < 2; ++nt2) {
            s16x8 a = *(const s16x8*)&Pt[nt2*16+l15][l4*8];
#pragma unroll
            for (int ot = 0; ot < 4; ++ot) {
                s16x8 b = *(const s16x8*)&Ws[wv*64+ot*16+l15][l4*8];
                oc2[nt2][ot] = __builtin_amdgcn_mfma_f32_16x16x32_bf16(a, b, oc2[nt2][ot], 0, 0, 0);
            }
        }
        __syncthreads();
    }
#pragma unroll
    for (int r = 0; r < 4; ++r) {
        float s = Lp[r];
        s += __shfl_xor(s, 1); s += __shfl_xor(s, 2);
        s += __shfl_xor(s, 4); s += __shfl_xor(s, 8);
        if (l15 == 0) L2[kh][nh*16 + l4*4 + r] = s;
    }
    __syncthreads();
#pragma unroll
    for (int nt2 = 0; nt2 < 2; ++nt2)
#pragma unroll
        for (int r = 0; r < 4; ++r) {
            int n = nt2*16 + l4*4 + r;
            float inv = 1.0f / (L2[0][n] + L2[1][n] + 1e-9f);
#pragma unroll
            for (int ot = 0; ot < 4; ++ot)
                out[(size_t)(nb+n)*O + wv*64 + ot*16 + l15] = oc2[nt2][ot][r] * inv;
        }
}

extern "C" void kernel_launch(void* const* d_in, const int* in_sizes, int n_in,
                              void* d_out, int out_size, void* d_ws, size_t ws_size,
                              hipStream_t stream) {
    const float* x   = (const float*)d_in[0];
    const float* cen = (const float*)d_in[1];
    const float* ls  = (const float*)d_in[2];
    const float* w   = (const float*)d_in[3];
    float* out = (float*)d_out;
    const int N = in_sizes[0] / D;   // 8192

    // ws layout
    size_t oXhi = 0;
    size_t oXlo = oXhi + (size_t)N * D * 2;
    size_t oChi = oXlo + (size_t)N * D * 2;
    size_t oClo = oChi + (size_t)K * D * 2;
    size_t oWb  = oClo + (size_t)K * D * 2;
    size_t oxs2 = oWb  + (size_t)O * K * 2;
    size_t oecs = oxs2 + (size_t)N * 4;
    size_t need = oecs + (size_t)K * 8;

    if (ws_size < need || (N % BN) != 0) {
        dim3 grid(N / FBN), block(NT);
        hipLaunchKernelGGL(rbf_fb, grid, block, 0, stream, x, cen, ls, w, out);
        return;
    }

    char* ws = (char*)d_ws;
    ushort* Xhi = (ushort*)(ws + oXhi);
    ushort* Xlo = (ushort*)(ws + oXlo);
    ushort* Chi = (ushort*)(ws + oChi);
    ushort* Clo = (ushort*)(ws + oClo);
    ushort* Wb  = (ushort*)(ws + oWb);
    float*  xs2 = (float*)(ws + oxs2);
    float2* ecs = (float2*)(ws + oecs);

    const int xb = (N * D / 4) / NT;         // blocks for X section
    dim3 pgrid(xb + 64 + (O * K / 4) / NT), pblock(NT);
    hipLaunchKernelGGL(rbf_prep, pgrid, pblock, 0, stream,
                       x, cen, ls, w, Xhi, Xlo, Chi, Clo, Wb, xs2, ecs, xb);

    dim3 grid(N / BN), block(NT);
    hipLaunchKernelGGL(rbf_main, grid, block, 0, stream,
                       Xhi, Xlo, Chi, Clo, Wb, xs2, ecs, out);
}